// Round 7
// baseline (263.036 us; speedup 1.0000x reference)
//
#include <hip/hip_runtime.h>
#include <math.h>

namespace {
constexpr int B = 4, N = 4, C = 64, H = 128, W = 256, L = 5;
constexpr int HW = H * W;
constexpr int WAVES = 16;         // waves per block (1024 threads)
constexpr int CPW = C / WAVES;    // channels per wave = 4
}

__global__ __launch_bounds__(1024, 8) void atten_comm_kernel(
    const float* __restrict__ x,    // (B*N, C, H, W)
    const float* __restrict__ P,    // (B, L, L, 4, 4)
    float* __restrict__ out)        // (B, C, H, W)
{
    __shared__ float sred[WAVES][N][64];

    const int b    = blockIdx.z;
    const int h    = blockIdx.y;
    const int lane = (int)(threadIdx.x & 63);
    const int wv   = (int)(threadIdx.x >> 6);
    const int w    = (blockIdx.x << 6) + lane;

    // normalized grid coords (align_corners=True)
    const float gx = -1.0f + (2.0f / (float)(W - 1)) * (float)w;
    const float gy = -1.0f + (2.0f / (float)(H - 1)) * (float)h;

    const float* basep[N];
    int   off[N][4];
    float wt[N][4];

#pragma unroll
    for (int n = 0; n < N; ++n) {
        // P[b, 0, n, r, c]; strides: b:L*L*16, i:L*16, j:16, r:4, c:1
        const float* p = P + ((size_t)b * L * L + (size_t)n) * 16;
        const float a  = p[0];
        const float bb = p[1] * ((float)H / (float)W);
        const float cc = p[3] * (2.0f / (4.0f * 0.4f * (float)W));
        const float d  = p[4] * ((float)W / (float)H);
        const float e  = p[5];
        const float ff = p[7] * (2.0f / (4.0f * 0.4f * (float)H));

        const float g0 = a * gx + bb * gy + cc;
        const float g1 = d * gx + e * gy + ff;
        const float ix = (g0 + 1.0f) * (0.5f * (float)(W - 1));
        const float iy = (g1 + 1.0f) * (0.5f * (float)(H - 1));

        const float fx0 = floorf(ix);
        const float fy0 = floorf(iy);
        const int x0 = (int)fx0, y0 = (int)fy0;
        const int x1 = x0 + 1,  y1 = y0 + 1;
        const float wx = ix - fx0;
        const float wy = iy - fy0;

        const int xc0 = min(max(x0, 0), W - 1);
        const int xc1 = min(max(x1, 0), W - 1);
        const int yc0 = min(max(y0, 0), H - 1);
        const int yc1 = min(max(y1, 0), H - 1);
        const float vx0 = (x0 >= 0 && x0 < W) ? 1.0f : 0.0f;
        const float vx1 = (x1 >= 0 && x1 < W) ? 1.0f : 0.0f;
        const float vy0 = (y0 >= 0 && y0 < H) ? 1.0f : 0.0f;
        const float vy1 = (y1 >= 0 && y1 < H) ? 1.0f : 0.0f;

        off[n][0] = yc0 * W + xc0;
        off[n][1] = yc0 * W + xc1;
        off[n][2] = yc1 * W + xc0;
        off[n][3] = yc1 * W + xc1;
        wt[n][0] = (1.0f - wx) * (1.0f - wy) * vx0 * vy0;
        wt[n][1] = wx * (1.0f - wy) * vx1 * vy0;
        wt[n][2] = (1.0f - wx) * wy * vx0 * vy1;
        wt[n][3] = wx * wy * vx1 * vy1;

        basep[n] = x + ((size_t)(b * N + n) * C + (size_t)(wv * CPW)) * HW;
    }

    // ---- gather: all 16 loads for a channel issued before the FMAs ----
    float f[N][CPW];
#pragma unroll
    for (int cc = 0; cc < CPW; ++cc) {
        float t[N][4];
#pragma unroll
        for (int n = 0; n < N; ++n) {
            const float* pl = basep[n] + (size_t)cc * HW;
            t[n][0] = pl[off[n][0]];
            t[n][1] = pl[off[n][1]];
            t[n][2] = pl[off[n][2]];
            t[n][3] = pl[off[n][3]];
        }
#pragma unroll
        for (int n = 0; n < N; ++n) {
            f[n][cc] = wt[n][0] * t[n][0] + wt[n][1] * t[n][1]
                     + wt[n][2] * t[n][2] + wt[n][3] * t[n][3];
        }
    }

    // ---- partial scores over this wave's channels ----
    float s[N] = {0.f, 0.f, 0.f, 0.f};
#pragma unroll
    for (int cc = 0; cc < CPW; ++cc) {
        const float q = f[0][cc];
#pragma unroll
        for (int n = 0; n < N; ++n) s[n] += q * f[n][cc];
    }

    // ---- cross-wave reduction via LDS (lane-stride-1, conflict-free) ----
#pragma unroll
    for (int n = 0; n < N; ++n) sred[wv][n][lane] = s[n];
    __syncthreads();

    float st[N];
#pragma unroll
    for (int n = 0; n < N; ++n) {
        float acc = 0.f;
#pragma unroll
        for (int v = 0; v < WAVES; ++v) acc += sred[v][n][lane];
        st[n] = acc;
    }

    const float scale = 0.125f;  // 1/sqrt(64)
    const float s0 = st[0] * scale, s1 = st[1] * scale;
    const float s2 = st[2] * scale, s3 = st[3] * scale;
    const float m  = fmaxf(fmaxf(s0, s1), fmaxf(s2, s3));
    const float e0 = expf(s0 - m);
    const float e1 = expf(s1 - m);
    const float e2 = expf(s2 - m);
    const float e3 = expf(s3 - m);
    const float inv = 1.0f / (e0 + e1 + e2 + e3);
    const float attn[N] = {e0 * inv, e1 * inv, e2 * inv, e3 * inv};

    // ---- context from registers + coalesced store ----
    float* op = out + ((size_t)b * C + (size_t)(wv * CPW)) * HW
                    + (size_t)h * W + (size_t)w;
#pragma unroll
    for (int cc = 0; cc < CPW; ++cc) {
        float ctx = 0.f;
#pragma unroll
        for (int n = 0; n < N; ++n) ctx += attn[n] * f[n][cc];
        op[(size_t)cc * HW] = ctx;
    }
}

extern "C" void kernel_launch(void* const* d_in, const int* in_sizes, int n_in,
                              void* d_out, int out_size, void* d_ws, size_t ws_size,
                              hipStream_t stream) {
    const float* x  = (const float*)d_in[0];
    const float* P  = (const float*)d_in[1];
    float* out = (float*)d_out;

    dim3 block(1024, 1, 1);
    dim3 grid(W / 64, H, B);  // (4, 128, 4) = 2048 blocks, 32768 waves
    hipLaunchKernelGGL(atten_comm_kernel, grid, block, 0, stream, x, P, out);
}

// Round 8
// 245.029 us; speedup vs baseline: 1.0735x; 1.0735x over previous
//
#include <hip/hip_runtime.h>
#include <math.h>

namespace {
constexpr int B = 4, N = 4, C = 64, H = 128, W = 256, L = 5;
constexpr int HW = H * W;
constexpr int WAVES = 8;          // waves per block
constexpr int CPW = C / WAVES;    // channels per wave = 8
}

// __launch_bounds__(512, 8): 8 waves/EU min -> 32 waves/CU target (4 blocks/CU),
// VGPR cap 64. Kernel measured 52 VGPR under (512,4), so no allocator pressure.
__global__ __launch_bounds__(512, 8) void atten_comm_kernel(
    const float* __restrict__ x,    // (B*N, C, H, W)
    const float* __restrict__ P,    // (B, L, L, 4, 4)
    float* __restrict__ out)        // (B, C, H, W)
{
    __shared__ float sred[WAVES][N][64];

    const int b    = blockIdx.z;
    const int h    = blockIdx.y;
    const int lane = (int)(threadIdx.x & 63);
    const int wv   = (int)(threadIdx.x >> 6);
    const int w    = (blockIdx.x << 6) + lane;

    // normalized grid coords (align_corners=True)
    const float gx = -1.0f + (2.0f / (float)(W - 1)) * (float)w;
    const float gy = -1.0f + (2.0f / (float)(H - 1)) * (float)h;

    const float* basep[N];
    int   off[N][4];
    float wt[N][4];

#pragma unroll
    for (int n = 0; n < N; ++n) {
        // P[b, 0, n, r, c]; strides: b:L*L*16, i:L*16, j:16, r:4, c:1
        const float* p = P + ((size_t)b * L * L + (size_t)n) * 16;
        const float a  = p[0];
        const float bb = p[1] * ((float)H / (float)W);
        const float cc = p[3] * (2.0f / (4.0f * 0.4f * (float)W));
        const float d  = p[4] * ((float)W / (float)H);
        const float e  = p[5];
        const float ff = p[7] * (2.0f / (4.0f * 0.4f * (float)H));

        const float g0 = a * gx + bb * gy + cc;
        const float g1 = d * gx + e * gy + ff;
        const float ix = (g0 + 1.0f) * (0.5f * (float)(W - 1));
        const float iy = (g1 + 1.0f) * (0.5f * (float)(H - 1));

        const float fx0 = floorf(ix);
        const float fy0 = floorf(iy);
        const int x0 = (int)fx0, y0 = (int)fy0;
        const int x1 = x0 + 1,  y1 = y0 + 1;
        const float wx = ix - fx0;
        const float wy = iy - fy0;

        const int xc0 = min(max(x0, 0), W - 1);
        const int xc1 = min(max(x1, 0), W - 1);
        const int yc0 = min(max(y0, 0), H - 1);
        const int yc1 = min(max(y1, 0), H - 1);
        const float vx0 = (x0 >= 0 && x0 < W) ? 1.0f : 0.0f;
        const float vx1 = (x1 >= 0 && x1 < W) ? 1.0f : 0.0f;
        const float vy0 = (y0 >= 0 && y0 < H) ? 1.0f : 0.0f;
        const float vy1 = (y1 >= 0 && y1 < H) ? 1.0f : 0.0f;

        off[n][0] = yc0 * W + xc0;
        off[n][1] = yc0 * W + xc1;
        off[n][2] = yc1 * W + xc0;
        off[n][3] = yc1 * W + xc1;
        wt[n][0] = (1.0f - wx) * (1.0f - wy) * vx0 * vy0;
        wt[n][1] = wx * (1.0f - wy) * vx1 * vy0;
        wt[n][2] = (1.0f - wx) * wy * vx0 * vy1;
        wt[n][3] = wx * wy * vx1 * vy1;

        basep[n] = x + ((size_t)(b * N + n) * C + (size_t)(wv * CPW)) * HW;
    }

    // ---- gather: all 16 loads for a channel issued before the FMAs ----
    float f[N][CPW];
#pragma unroll
    for (int cc = 0; cc < CPW; ++cc) {
        float t[N][4];
#pragma unroll
        for (int n = 0; n < N; ++n) {
            const float* pl = basep[n] + (size_t)cc * HW;
            t[n][0] = pl[off[n][0]];
            t[n][1] = pl[off[n][1]];
            t[n][2] = pl[off[n][2]];
            t[n][3] = pl[off[n][3]];
        }
#pragma unroll
        for (int n = 0; n < N; ++n) {
            f[n][cc] = wt[n][0] * t[n][0] + wt[n][1] * t[n][1]
                     + wt[n][2] * t[n][2] + wt[n][3] * t[n][3];
        }
    }

    // ---- partial scores over this wave's channels ----
    float s[N] = {0.f, 0.f, 0.f, 0.f};
#pragma unroll
    for (int cc = 0; cc < CPW; ++cc) {
        const float q = f[0][cc];
#pragma unroll
        for (int n = 0; n < N; ++n) s[n] += q * f[n][cc];
    }

    // ---- cross-wave reduction via LDS (lane-stride-1, conflict-free) ----
#pragma unroll
    for (int n = 0; n < N; ++n) sred[wv][n][lane] = s[n];
    __syncthreads();

    float st[N];
#pragma unroll
    for (int n = 0; n < N; ++n) {
        float acc = 0.f;
#pragma unroll
        for (int v = 0; v < WAVES; ++v) acc += sred[v][n][lane];
        st[n] = acc;
    }

    const float scale = 0.125f;  // 1/sqrt(64)
    const float s0 = st[0] * scale, s1 = st[1] * scale;
    const float s2 = st[2] * scale, s3 = st[3] * scale;
    const float m  = fmaxf(fmaxf(s0, s1), fmaxf(s2, s3));
    const float e0 = expf(s0 - m);
    const float e1 = expf(s1 - m);
    const float e2 = expf(s2 - m);
    const float e3 = expf(s3 - m);
    const float inv = 1.0f / (e0 + e1 + e2 + e3);
    const float attn[N] = {e0 * inv, e1 * inv, e2 * inv, e3 * inv};

    // ---- context from registers + coalesced store ----
    float* op = out + ((size_t)b * C + (size_t)(wv * CPW)) * HW
                    + (size_t)h * W + (size_t)w;
#pragma unroll
    for (int cc = 0; cc < CPW; ++cc) {
        float ctx = 0.f;
#pragma unroll
        for (int n = 0; n < N; ++n) ctx += attn[n] * f[n][cc];
        op[(size_t)cc * HW] = ctx;
    }
}

extern "C" void kernel_launch(void* const* d_in, const int* in_sizes, int n_in,
                              void* d_out, int out_size, void* d_ws, size_t ws_size,
                              hipStream_t stream) {
    const float* x  = (const float*)d_in[0];
    const float* P  = (const float*)d_in[1];
    float* out = (float*)d_out;

    dim3 block(512, 1, 1);
    dim3 grid(W / 64, H, B);  // (4, 128, 4) = 2048 blocks, 16384 waves
    hipLaunchKernelGGL(atten_comm_kernel, grid, block, 0, stream, x, P, out);
}

// Round 9
// 61.473 us; speedup vs baseline: 4.2789x; 3.9860x over previous
//
#include <hip/hip_runtime.h>
#include <math.h>

namespace {
constexpr int B = 4, N = 4, C = 64, H = 128, W = 256, L = 5;
constexpr int HW = H * W;
constexpr int WAVES = 8;          // waves per block
constexpr int CPW = C / WAVES;    // channels per wave = 8
}

// 8-byte pair load with only 4-byte alignment guarantee (x-taps are adjacent).
typedef float f2v __attribute__((ext_vector_type(2), aligned(4)));

__global__ __launch_bounds__(512, 4) void atten_comm_kernel(
    const float* __restrict__ x,    // (B*N, C, H, W)
    const float* __restrict__ P,    // (B, L, L, 4, 4)
    float* __restrict__ out)        // (B, C, H, W)
{
    __shared__ float sred[WAVES][N][64];

    const int b    = blockIdx.z;
    const int h    = blockIdx.y;
    const int lane = (int)(threadIdx.x & 63);
    const int wv   = (int)(threadIdx.x >> 6);
    const int w    = (blockIdx.x << 6) + lane;

    // normalized grid coords (align_corners=True)
    const float gx = -1.0f + (2.0f / (float)(W - 1)) * (float)w;
    const float gy = -1.0f + (2.0f / (float)(H - 1)) * (float)h;

    const float* basep[N];
    int   voff0[N], voff1[N];               // element offsets of the two row pairs
    float u0x[N], u0y[N], u1x[N], u1y[N];   // folded bilinear+boundary weights

#pragma unroll
    for (int n = 0; n < N; ++n) {
        // P[b, 0, n, r, c]; strides: b:L*L*16, i:L*16, j:16, r:4, c:1
        const float* p = P + ((size_t)b * L * L + (size_t)n) * 16;
        const float a  = p[0];
        const float bb = p[1] * ((float)H / (float)W);
        const float cc = p[3] * (2.0f / (4.0f * 0.4f * (float)W));
        const float d  = p[4] * ((float)W / (float)H);
        const float e  = p[5];
        const float ff = p[7] * (2.0f / (4.0f * 0.4f * (float)H));

        const float g0 = a * gx + bb * gy + cc;
        const float g1 = d * gx + e * gy + ff;
        const float ix = (g0 + 1.0f) * (0.5f * (float)(W - 1));
        const float iy = (g1 + 1.0f) * (0.5f * (float)(H - 1));

        const float fx0 = floorf(ix);
        const float fy0 = floorf(iy);
        const int x0 = (int)fx0, y0 = (int)fy0;
        const int y1 = y0 + 1;
        const float wx = ix - fx0;
        const float wy = iy - fy0;

        // x-pair: load (xa, xa+1); both x-taps live in this window with
        // boundary cases folded into (ux, uy):
        const int   xa   = min(max(x0, 0), W - 2);
        const float wx0v = (1.0f - wx) * ((x0 >= 0 && x0 < W) ? 1.0f : 0.0f);
        const float wx1v = wx * ((x0 + 1 >= 0 && x0 + 1 < W) ? 1.0f : 0.0f);
        // interior: (wx0v, wx1v); x0==-1: taps shift left -> (wx1v, 0);
        // x0==W-1: taps shift right -> (0, wx0v); fully OOB collapses to 0.
        const float ux = (x0 < 0) ? wx1v : ((x0 > W - 2) ? 0.0f : wx0v);
        const float uy = (x0 < 0) ? 0.0f : ((x0 > W - 2) ? wx0v : wx1v);

        const int yc0 = min(max(y0, 0), H - 1);
        const int yc1 = min(max(y1, 0), H - 1);
        const float wyv0 = (1.0f - wy) * ((y0 >= 0 && y0 < H) ? 1.0f : 0.0f);
        const float wyv1 = wy * ((y1 >= 0 && y1 < H) ? 1.0f : 0.0f);

        u0x[n] = ux * wyv0;  u0y[n] = uy * wyv0;
        u1x[n] = ux * wyv1;  u1y[n] = uy * wyv1;
        voff0[n] = yc0 * W + xa;
        voff1[n] = yc1 * W + xa;

        basep[n] = x + ((size_t)(b * N + n) * C + (size_t)(wv * CPW)) * HW;
    }

    // ---- gather: 8 pair-loads per channel issued before the FMAs ----
    float f[N][CPW];
#pragma unroll
    for (int cc = 0; cc < CPW; ++cc) {
        f2v t0[N], t1[N];
#pragma unroll
        for (int n = 0; n < N; ++n) {
            const float* pl = basep[n] + (size_t)cc * HW;
            t0[n] = *(const f2v*)(pl + voff0[n]);
            t1[n] = *(const f2v*)(pl + voff1[n]);
        }
#pragma unroll
        for (int n = 0; n < N; ++n) {
            f[n][cc] = u0x[n] * t0[n].x + u0y[n] * t0[n].y
                     + u1x[n] * t1[n].x + u1y[n] * t1[n].y;
        }
    }

    // ---- partial scores over this wave's channels ----
    float s[N] = {0.f, 0.f, 0.f, 0.f};
#pragma unroll
    for (int cc = 0; cc < CPW; ++cc) {
        const float q = f[0][cc];
#pragma unroll
        for (int n = 0; n < N; ++n) s[n] += q * f[n][cc];
    }

    // ---- cross-wave reduction via LDS (lane-stride-1, conflict-free) ----
#pragma unroll
    for (int n = 0; n < N; ++n) sred[wv][n][lane] = s[n];
    __syncthreads();

    float st[N];
#pragma unroll
    for (int n = 0; n < N; ++n) {
        float acc = 0.f;
#pragma unroll
        for (int v = 0; v < WAVES; ++v) acc += sred[v][n][lane];
        st[n] = acc;
    }

    const float scale = 0.125f;  // 1/sqrt(64)
    const float s0 = st[0] * scale, s1 = st[1] * scale;
    const float s2 = st[2] * scale, s3 = st[3] * scale;
    const float m  = fmaxf(fmaxf(s0, s1), fmaxf(s2, s3));
    const float e0 = expf(s0 - m);
    const float e1 = expf(s1 - m);
    const float e2 = expf(s2 - m);
    const float e3 = expf(s3 - m);
    const float inv = 1.0f / (e0 + e1 + e2 + e3);
    const float attn[N] = {e0 * inv, e1 * inv, e2 * inv, e3 * inv};

    // ---- context from registers + coalesced store ----
    float* op = out + ((size_t)b * C + (size_t)(wv * CPW)) * HW
                    + (size_t)h * W + (size_t)w;
#pragma unroll
    for (int cc = 0; cc < CPW; ++cc) {
        float ctx = 0.f;
#pragma unroll
        for (int n = 0; n < N; ++n) ctx += attn[n] * f[n][cc];
        op[(size_t)cc * HW] = ctx;
    }
}

extern "C" void kernel_launch(void* const* d_in, const int* in_sizes, int n_in,
                              void* d_out, int out_size, void* d_ws, size_t ws_size,
                              hipStream_t stream) {
    const float* x  = (const float*)d_in[0];
    const float* P  = (const float*)d_in[1];
    float* out = (float*)d_out;

    dim3 block(512, 1, 1);
    dim3 grid(W / 64, H, B);  // (4, 128, 4) = 2048 blocks, 16384 waves
    hipLaunchKernelGGL(atten_comm_kernel, grid, block, 0, stream, x, P, out);
}